// Round 12
// baseline (441.028 us; speedup 1.0000x reference)
//
#include <hip/hip_runtime.h>

#define NN 100000
#define EE 1600000
#define IN_F 24
#define HID 128
#define OUT_F 12
#define LBLK 128        // rows per fused block

#define NBKT 782        // dst buckets of 128 nodes
#define PA_BLKS 256     // bucket-count / scatter blocks
#define PA_EPB 6250     // EE / PA_BLKS

#define OW_BITS 15
#define OWIN 32768      // out-deg window (64KB packed-u16 LDS)
#define OW_GRP 4        // ceil(NN/OWIN)
#define OW_CPY 64       // copies per window
#define OW_EPB 25000    // EE / OW_CPY

#define EMB_B 2048
#define PREP_B 264
#define ONORM_B 196     // ceil((NN/2)/256)
#define K1_GRID (PA_BLKS + EMB_B + PREP_B + ONORM_B)   // 2764

typedef unsigned char u8;
typedef unsigned short u16;
typedef unsigned int u32;
typedef unsigned long long u64;

using short8 = __attribute__((ext_vector_type(8))) short;
using f32x4  = __attribute__((ext_vector_type(4))) float;

__device__ __forceinline__ float bf2f(u16 h) {
  return __uint_as_float(((u32)h) << 16);
}
__device__ __forceinline__ u16 f2bf(float f) {
  u32 u = __float_as_uint(f);
  u32 r = (u + 0x7FFFu + ((u >> 16) & 1u)) >> 16;   // RNE
  return (u16)r;
}
__device__ __forceinline__ float inv_sqrt_cnt(int c) {
  if (c < 1) c = 1;
  return 1.0f / sqrtf((float)c);
}

// ---------- out-degree: windowed packed-u16 LDS histograms (no scatter) ----------
__global__ __launch_bounds__(256) void k_odeg(const int* __restrict__ src,
                                              u32* __restrict__ whist) {
  __shared__ u32 hist[OWIN / 2];   // 64KB: u16 pair per u32
  int b = blockIdx.x, t = threadIdx.x;
  int g = b >> 6, sb = b & 63;
  for (int i = t; i < OWIN / 2; i += 256) hist[i] = 0;
  __syncthreads();
  int e0 = sb * OW_EPB;
  for (int e = e0 + t; e < e0 + OW_EPB; e += 256) {
    int s = src[e];
    if ((s >> OW_BITS) == g) {
      int i = s & (OWIN - 1);
      atomicAdd(&hist[i >> 1], (i & 1) ? 0x10000u : 1u);
    }
  }
  __syncthreads();
  u32* out = whist + (size_t)b * (OWIN / 2);
  for (int i = t; i < OWIN / 2; i += 256) out[i] = hist[i];
}

// ---------- K1 sub-bodies ----------
__device__ __forceinline__ void emb_body(int eb, const float* __restrict__ inputs,
                                         const float* __restrict__ W_emb,
                                         const float* __restrict__ b_emb,
                                         u16* __restrict__ harr, float* smemW) {
  int t = threadIdx.x;
  float* Wls = smemW;
  float* bls = smemW + IN_F * HID;
  for (int i = t; i < IN_F * HID; i += 256) Wls[i] = W_emb[i];
  if (t < HID) bls[t] = b_emb[t];
  __syncthreads();
  int c = t & 127;
  int sub = t >> 7;
  for (int node = eb * 2 + sub; node < NN; node += EMB_B * 2) {
    const float* xr = inputs + (size_t)node * IN_F;
    float acc = bls[c];
    #pragma unroll
    for (int k = 0; k < IN_F; ++k) acc = fmaf(xr[k], Wls[k * HID + c], acc);
    harr[(size_t)node * HID + c] = f2bf(acc);
  }
}

__device__ __forceinline__ void prep_body(int pb,
    const float* __restrict__ Ws1, const float* __restrict__ W1m,
    const float* __restrict__ Ws2, const float* __restrict__ W2m,
    const float* __restrict__ Wfc,
    u16* __restrict__ WT1, u16* __restrict__ WT2, u16* __restrict__ WfcT) {
  int idx = pb * 256 + (int)threadIdx.x;
  if (idx < 65536) {
    int layer = idx >> 15;
    int rem = idx & 32767;
    int n = rem >> 8, k = rem & 255;
    const float* A = layer ? Ws2 : Ws1;
    const float* B = layer ? W2m : W1m;
    float v = (k < HID) ? A[(size_t)k * HID + n] : B[(size_t)(k - HID) * HID + n];
    (layer ? WT2 : WT1)[(size_t)n * 256 + k] = f2bf(v);
  } else if (idx < 65536 + 2048) {
    int j = idx - 65536;
    int n = j >> 7, k = j & 127;
    WfcT[(size_t)n * 128 + k] = f2bf(n < OUT_F ? Wfc[(size_t)k * OUT_F + n] : 0.f);
  }
}

__device__ __forceinline__ void onorm_body(int ob, const u32* __restrict__ whist,
                                           float* __restrict__ out_norm) {
  int i = ob * 256 + (int)threadIdx.x;   // packed node pair
  if (i >= NN / 2) return;
  int n0 = 2 * i;
  int g = n0 >> OW_BITS;
  int pi = (n0 & (OWIN - 1)) >> 1;
  const u32* base = whist + (size_t)(g * OW_CPY) * (OWIN / 2) + pi;
  u32 s = 0;
  #pragma unroll 8
  for (int c = 0; c < OW_CPY; ++c) s += base[(size_t)c * (OWIN / 2)];
  out_norm[n0]     = inv_sqrt_cnt((int)(s & 0xFFFFu));
  out_norm[n0 + 1] = inv_sqrt_cnt((int)(s >> 16));
}

// K1: fused [dst bucket-count | emb | weight prep | out-norm merge]
__global__ __launch_bounds__(256) void k1(
    const int* __restrict__ dst, u32* __restrict__ histgD,
    const float* __restrict__ inputs, const float* __restrict__ W_emb,
    const float* __restrict__ b_emb, u16* __restrict__ harr,
    const float* __restrict__ Ws1, const float* __restrict__ W1m,
    const float* __restrict__ Ws2, const float* __restrict__ W2m,
    const float* __restrict__ Wfc,
    u16* __restrict__ WT1, u16* __restrict__ WT2, u16* __restrict__ WfcT,
    const u32* __restrict__ whist, float* __restrict__ out_norm) {
  __shared__ __align__(16) char sm[13312];
  int b = blockIdx.x, t = threadIdx.x;
  if (b < PA_BLKS) {
    u32* histD = (u32*)sm;
    for (int i = t; i < 1024; i += 256) histD[i] = 0;
    __syncthreads();
    int e0 = b * PA_EPB;
    for (int e = e0 + t; e < e0 + PA_EPB; e += 256)
      atomicAdd(&histD[dst[e] >> 7], 1u);
    __syncthreads();
    for (int i = t; i < 1024; i += 256) histgD[(size_t)b * 1024 + i] = histD[i];
  } else if (b < PA_BLKS + EMB_B) {
    emb_body(b - PA_BLKS, inputs, W_emb, b_emb, harr, (float*)sm);
  } else if (b < PA_BLKS + EMB_B + PREP_B) {
    prep_body(b - PA_BLKS - EMB_B, Ws1, W1m, Ws2, W2m, Wfc, WT1, WT2, WfcT);
  } else {
    onorm_body(b - PA_BLKS - EMB_B - PREP_B, whist, out_norm);
  }
}

// scan1: per bucket k, exclusive scan over the 256 passA blocks (in-place) + total
__global__ __launch_bounds__(256) void k_scan1(u32* __restrict__ histgD,
                                               u32* __restrict__ totalsD) {
  __shared__ u32 s[256];
  int k = blockIdx.x, t = threadIdx.x;
  u32 v = histgD[(size_t)t * 1024 + k];
  s[t] = v;
  __syncthreads();
  for (int off = 1; off < 256; off <<= 1) {
    u32 a = (t >= off) ? s[t - off] : 0;
    __syncthreads();
    s[t] += a;
    __syncthreads();
  }
  histgD[(size_t)t * 1024 + k] = s[t] - v;   // exclusive
  if (t == 255) totalsD[k] = s[255];
}

// scan2: exclusive scan over bucket totals -> estart[0..NBKT]
__global__ __launch_bounds__(1024) void k_scan2(const u32* __restrict__ totalsD,
                                                u32* __restrict__ estartD) {
  __shared__ u32 s[1024];
  int t = threadIdx.x;
  u32 v = (t < NBKT) ? totalsD[t] : 0;
  s[t] = v;
  __syncthreads();
  for (int off = 1; off < 1024; off <<= 1) {
    u32 a = (t >= off) ? s[t - off] : 0;
    __syncthreads();
    s[t] += a;
    __syncthreads();
  }
  if (t < NBKT) estartD[t] = s[t] - v;
  if (t == NBKT - 1) estartD[NBKT] = s[t];
}

// passB: scatter u64 edge records to bucket order via LDS cursors.
__global__ __launch_bounds__(256) void k_passb(
    const int* __restrict__ src, const int* __restrict__ dst,
    const float* __restrict__ e_w,
    const u32* __restrict__ histgD, const u32* __restrict__ estartD,
    u64* __restrict__ ebuf) {
  __shared__ u32 cur[1024];
  int pb = blockIdx.x, t = threadIdx.x;
  for (int i = t; i < 1024; i += 256)
    cur[i] = ((i < NBKT) ? estartD[i] : 0u) + histgD[(size_t)pb * 1024 + i];
  __syncthreads();
  int e0 = pb * PA_EPB;
  for (int e = e0 + t; e < e0 + PA_EPB; e += 256) {
    int s = src[e], d = dst[e];
    u32 hi = (u32)s | (((u32)(d & 127)) << 17);
    u64 rec = ((u64)hi << 32) | (u64)__float_as_uint(e_w[e]);
    u32 pos = atomicAdd(&cur[d >> 7], 1u);   // LDS atomic
    ebuf[pos] = rec;
  }
}

// reorder: within-bucket counting sort IN PLACE via LDS staging.
#define RCAP 2560
__global__ __launch_bounds__(256) void k_reorder(
    u64* __restrict__ ebuf, const u32* __restrict__ estart,
    int* __restrict__ row_start, float* __restrict__ in_norm) {
  __shared__ u64 stage[RCAP];
  __shared__ u32 cnt[128], pfx[128], cur[128];
  int k = blockIdx.x, t = threadIdx.x;
  if (t < 128) cnt[t] = 0;
  __syncthreads();
  int e0 = (int)estart[k], e1 = (int)estart[k + 1];
  int n = e1 - e0; if (n > RCAP) n = RCAP;   // 11-sigma impossible
  for (int i = t; i < n; i += 256) {
    u64 v = ebuf[e0 + i];
    stage[i] = v;
    atomicAdd(&cnt[(u32)(v >> 49) & 127], 1u);
  }
  __syncthreads();
  if (t < 128) pfx[t] = cnt[t];
  __syncthreads();
  for (int off = 1; off < 128; off <<= 1) {
    u32 v = (t < 128 && t >= off) ? pfx[t - off] : 0;
    __syncthreads();
    if (t < 128) pfx[t] += v;
    __syncthreads();
  }
  if (t < 128) {
    u32 start = (u32)e0 + pfx[t] - cnt[t];
    cur[t] = start;
    int node = k * 128 + t;
    if (node < NN) {
      row_start[node] = (int)start;
      in_norm[node] = inv_sqrt_cnt((int)cnt[t]);
    }
  }
  if (k == NBKT - 1 && t == 0) row_start[NN] = e1;
  __syncthreads();
  for (int i = t; i < n; i += 256) {
    u64 v = stage[i];
    u32 pos = atomicAdd(&cur[(u32)(v >> 49) & 127], 1u);
    ebuf[pos] = v;
  }
}

// ---------- FUSED [agg -> LDS | MFMA layer GEMM | optional FC] ----------
// Block b: agg for nodes [b*128,(b+1)*128) written straight into the LDS X
// agg-half; then the 128x128xK=256 GEMM.
// RACE FIX (r11): reads hin, writes hout (FC=0) — never in-place. Other
// blocks' gathers read hin, which is immutable during this kernel.
template<int FC>
__global__ __launch_bounds__(512) void k_fused(const u16* __restrict__ hin,
    u16* __restrict__ hout,
    const int* __restrict__ row_start, const float* __restrict__ in_norm,
    const float* __restrict__ out_norm, const u64* __restrict__ ebuf,
    const u16* __restrict__ WT, const float* __restrict__ bias,
    const u16* __restrict__ WfcT, const float* __restrict__ b_fc,
    float* __restrict__ out) {
  __shared__ char smem[135168];
  const int t = threadIdx.x;
  const int r0 = blockIdx.x * LBLK;

  #pragma unroll
  for (int i = 0; i < 8; ++i) {      // stage W (64KB)
    int boff = i * 8192 + t * 16;
    int row = boff >> 9, col = boff & 511;
    uint4 v = *(const uint4*)(WT + (size_t)row * 256 + (col >> 1));
    *(uint4*)(smem + 65536 + row * 512 + (col ^ ((row & 7) << 4))) = v;
  }
  if (FC && t < 256) {               // stage WfcT (4KB)
    int row = t >> 4, col = (t & 15) * 16;
    uint4 v = *(const uint4*)(WfcT + (size_t)row * 128 + (col >> 1));
    *(uint4*)(smem + 131072 + row * 256 + (col ^ ((row & 7) << 4))) = v;
  }
  #pragma unroll
  for (int i = 0; i < 4; ++i) {      // stage X h-half (32KB); tail OOB reads in-ws, benign
    int boff = i * 8192 + t * 16;
    int row = boff >> 8, col = boff & 255;
    uint4 v = *(const uint4*)(hin + (size_t)(r0 + row) * HID + (col >> 1));
    *(uint4*)(smem + row * 512 + (col ^ ((row & 7) << 4))) = v;
  }

  // ---- agg phase: 16 groups x 32 lanes, 8 nodes per group, 8-deep MLP ----
  {
    const int grp = t >> 5, lane = t & 31;
    for (int i = 0; i < 8; ++i) {
      int lrow = grp * 8 + i;
      int node = r0 + lrow;
      float a0 = 0.f, a1 = 0.f, a2 = 0.f, a3 = 0.f;
      float inn = 0.f;
      if (node < NN) {
        inn = in_norm[node];
        int s0 = row_start[node], s1 = row_start[node + 1];
        for (int i0 = s0; i0 < s1; i0 += 32) {
          u32 pk2 = 0;
          if (i0 + lane < s1) {
            u64 rec = ebuf[i0 + lane];
            u32 sv = (u32)(rec >> 32) & 0x1FFFF;
            float w = __uint_as_float((u32)rec) * out_norm[sv];
            pk2 = (((u32)f2bf(w)) << 17) | sv;
          }
          int m = s1 - i0; if (m > 32) m = 32;
          int j = 0;
          for (; j + 8 <= m; j += 8) {
            ushort4 hv[8]; float wq[8];
            #pragma unroll
            for (int q = 0; q < 8; ++q) {
              u32 p = __shfl(pk2, j + q, 32);
              wq[q] = bf2f((u16)(p >> 17));
              hv[q] = *(const ushort4*)(hin + (size_t)(p & 0x1FFFF) * HID + lane * 4);
            }
            #pragma unroll
            for (int q = 0; q < 8; ++q) {
              a0 = fmaf(wq[q], bf2f(hv[q].x), a0);
              a1 = fmaf(wq[q], bf2f(hv[q].y), a1);
              a2 = fmaf(wq[q], bf2f(hv[q].z), a2);
              a3 = fmaf(wq[q], bf2f(hv[q].w), a3);
            }
          }
          for (; j < m; ++j) {
            u32 p = __shfl(pk2, j, 32);
            float w = bf2f((u16)(p >> 17));
            ushort4 hv = *(const ushort4*)(hin + (size_t)(p & 0x1FFFF) * HID + lane * 4);
            a0 = fmaf(w, bf2f(hv.x), a0);
            a1 = fmaf(w, bf2f(hv.y), a1);
            a2 = fmaf(w, bf2f(hv.z), a2);
            a3 = fmaf(w, bf2f(hv.w), a3);
          }
        }
      }
      ushort4 r;
      r.x = f2bf(a0 * inn); r.y = f2bf(a1 * inn);
      r.z = f2bf(a2 * inn); r.w = f2bf(a3 * inn);
      int c2 = lane * 8;   // byte offset within the 256B agg half
      *(ushort4*)(smem + lrow * 512 + 256 + (c2 ^ ((lrow & 7) << 4))) = r;
    }
  }
  __syncthreads();

  // ---- GEMM phase (proven) ----
  const int lane = t & 63, w = t >> 6;
  const int l15 = lane & 15, lhi = lane >> 4;

  f32x4 acc[8];
  #pragma unroll
  for (int nf = 0; nf < 8; ++nf) acc[nf] = (f32x4){0.f, 0.f, 0.f, 0.f};

  const int arow = w * 16 + l15;
  const char* pa = smem + arow * 512;
  const int aswz = (arow & 7) << 4;
  #pragma unroll
  for (int ks = 0; ks < 8; ++ks) {
    int kb = ks * 64 + (lhi << 4);
    short8 a = *(const short8*)(pa + (kb ^ aswz));
    #pragma unroll
    for (int nf = 0; nf < 8; ++nf) {
      int brow = nf * 16 + l15;
      short8 bf = *(const short8*)(smem + 65536 + brow * 512 + (kb ^ ((brow & 7) << 4)));
      acc[nf] = __builtin_amdgcn_mfma_f32_16x16x32_bf16(a, bf, acc[nf], 0, 0, 0);
    }
  }

  float bcol[8];
  #pragma unroll
  for (int nf = 0; nf < 8; ++nf) bcol[nf] = bias[nf * 16 + l15];

  if (!FC) {
    #pragma unroll
    for (int r = 0; r < 4; ++r) {
      int grow = r0 + w * 16 + (lhi << 2) + r;
      if (grow < NN) {
        float inn = in_norm[grow];
        #pragma unroll
        for (int nf = 0; nf < 8; ++nf) {
          float v = acc[nf][r] + inn * bcol[nf];
          hout[(size_t)grow * HID + nf * 16 + l15] = f2bf(fmaxf(v, 0.f));
        }
      }
    }
  } else {
    __syncthreads();   // h2 overlays X rows: wait until all waves done reading X
    #pragma unroll
    for (int r = 0; r < 4; ++r) {
      int lrow = w * 16 + (lhi << 2) + r;
      int grow = r0 + lrow;
      float inn = (grow < NN) ? in_norm[grow] : 0.f;
      #pragma unroll
      for (int nf = 0; nf < 8; ++nf) {
        int col = nf * 16 + l15;
        float v = fmaxf(acc[nf][r] + inn * bcol[nf], 0.f);
        *(u16*)(smem + lrow * 256 + ((col * 2) ^ ((lrow & 7) << 4))) = f2bf(v);
      }
    }
    __syncthreads();
    f32x4 a2 = (f32x4){0.f, 0.f, 0.f, 0.f};
    const char* pa2 = smem + (w * 16 + l15) * 256;
    const int as2 = (l15 & 7) << 4;
    #pragma unroll
    for (int ks = 0; ks < 4; ++ks) {
      int kb = ks * 64 + (lhi << 4);
      short8 a = *(const short8*)(pa2 + (kb ^ as2));
      short8 bf = *(const short8*)(smem + 131072 + l15 * 256 + (kb ^ as2));
      a2 = __builtin_amdgcn_mfma_f32_16x16x32_bf16(a, bf, a2, 0, 0, 0);
    }
    if (l15 < OUT_F) {
      float bo = b_fc[l15];
      #pragma unroll
      for (int r = 0; r < 4; ++r) {
        int grow = r0 + w * 16 + (lhi << 2) + r;
        if (grow < NN) out[(size_t)grow * OUT_F + l15] = a2[r] + bo;
      }
    }
  }
}

extern "C" void kernel_launch(void* const* d_in, const int* in_sizes, int n_in,
                              void* d_out, int out_size, void* d_ws, size_t ws_size,
                              hipStream_t stream) {
  (void)in_sizes; (void)n_in; (void)out_size;
  const float* inputs  = (const float*)d_in[0];
  const int*   src     = (const int*)d_in[1];
  const int*   dst     = (const int*)d_in[2];
  const float* e_w     = (const float*)d_in[3];
  const float* W_emb   = (const float*)d_in[6];
  const float* b_emb   = (const float*)d_in[7];
  const float* W_self1 = (const float*)d_in[8];
  const float* W1      = (const float*)d_in[9];
  const float* b1      = (const float*)d_in[10];
  const float* W_self2 = (const float*)d_in[11];
  const float* W2      = (const float*)d_in[12];
  const float* b2      = (const float*)d_in[13];
  const float* W_fc    = (const float*)d_in[14];
  const float* b_fc    = (const float*)d_in[15];
  float* out = (float*)d_out;

  // layout (65.8 MB < proven 72.2 MB):
  // [out_norm | in_norm | row_start | ebuf 12.8M | harr(h0) 25.6M | WTs 0.14M
  //  | REGION_Z 25.6M]
  // REGION_Z holds hb(h1, full 25.6M) OVERLAYING {histgD 1M, totals, estart,
  // whist 16.8M} — all dead before k_fused<0> (first writer of hb):
  //   histgD dead after k_passb; whist dead after k1; estart dead after k_reorder.
  float* out_norm  = (float*)d_ws;                       // NN
  float* in_norm   = out_norm + NN;                      // NN
  int* row_start   = (int*)(in_norm + NN);               // NN+4
  u64* ebuf        = (u64*)(row_start + NN + 4);         // EE u64
  u16* harr        = (u16*)(ebuf + EE);                  // NN*HID u16
  u16* WT1         = harr + (size_t)NN * HID;
  u16* WT2         = WT1 + 32768;
  u16* WfcT        = WT2 + 32768;
  char* regZ       = (char*)(WfcT + 2048);
  u16* hb          = (u16*)regZ;                         // NN*HID u16 (h1)
  u32* histgD      = (u32*)regZ;                         // overlay head
  u32* totalsD     = histgD + (size_t)PA_BLKS * 1024;
  u32* estartD     = totalsD + 1024;
  u32* whist       = estartD + 1024;                     // 256*16384 u32

  const size_t Z_NEED = (size_t)NN * HID * 2;            // 25.6M (> 17.8M overlay)
  const size_t NEED = (size_t)(3 * NN + 4) * 4 + (size_t)EE * 8
                      + (size_t)NN * HID * 2 + (2 * 32768 + 2048) * 2 + Z_NEED;
  if (ws_size < NEED) return;

  hipLaunchKernelGGL(k_odeg, dim3(OW_GRP * OW_CPY), dim3(256), 0, stream, src, whist);
  hipLaunchKernelGGL(k1, dim3(K1_GRID), dim3(256), 0, stream,
                     dst, histgD, inputs, W_emb, b_emb, harr,
                     W_self1, W1, W_self2, W2, W_fc, WT1, WT2, WfcT,
                     whist, out_norm);
  hipLaunchKernelGGL(k_scan1, dim3(NBKT), dim3(256), 0, stream, histgD, totalsD);
  hipLaunchKernelGGL(k_scan2, dim3(1), dim3(1024), 0, stream, totalsD, estartD);
  hipLaunchKernelGGL(k_passb, dim3(PA_BLKS), dim3(256), 0, stream,
                     src, dst, e_w, histgD, estartD, ebuf);
  hipLaunchKernelGGL(k_reorder, dim3(NBKT), dim3(256), 0, stream,
                     ebuf, estartD, row_start, in_norm);
  // layer 1 (fused agg + GEMM): reads h0=harr, writes h1=hb
  hipLaunchKernelGGL(k_fused<0>, dim3(NBKT), dim3(512), 0, stream,
                     harr, hb, row_start, in_norm, out_norm, ebuf,
                     WT1, b1, WfcT, b_fc, out);
  // layer 2 (fused agg + GEMM + FC): reads h1=hb, writes only `out`
  hipLaunchKernelGGL(k_fused<1>, dim3(NBKT), dim3(512), 0, stream,
                     hb, (u16*)nullptr, row_start, in_norm, out_norm, ebuf,
                     WT2, b2, WfcT, b_fc, out);
}